// Round 1
// baseline (25998.935 us; speedup 1.0000x reference)
//
#include <hip/hip_runtime.h>
#include <math.h>

#define B   64
#define T   64
#define TS  63
#define V   32000
#define E   512
#define H   1024
#define EH  2048

__device__ __forceinline__ float sigmoidf_(float x) {
    return 1.0f / (1.0f + expf(-x));
}

// initial_state (B, EH) -> sT (EH, B)
__global__ __launch_bounds__(256) void transpose_init_kernel(
    const float* __restrict__ s, float* __restrict__ sT) {
    int idx = blockIdx.x * 256 + threadIdx.x;   // idx over EH*B
    int b = idx & (B - 1);
    int k = idx >> 6;
    sT[idx] = s[b * EH + k];
}

// h0 = initial_state @ enc_proj_W.T, written transposed to 4 state buffers.
// One wave per j, lane = b.
__global__ __launch_bounds__(256) void encoder_kernel(
    const float* __restrict__ sT, const float* __restrict__ encW,
    float* __restrict__ h0_init, float* __restrict__ h1_init,
    float* __restrict__ c0T, float* __restrict__ c1T) {
    const int lane = threadIdx.x & 63;
    int jw = blockIdx.x * 4 + (threadIdx.x >> 6);
    const int j = __builtin_amdgcn_readfirstlane(jw);
    const float* w = encW + (size_t)j * EH;
    float acc = 0.0f;
    #pragma unroll 4
    for (int k = 0; k < EH; ++k) {
        acc = fmaf(sT[k * B + lane], w[k], acc);
    }
    int off = j * B + lane;
    h0_init[off] = acc;
    h1_init[off] = acc;
    c0T[off] = acc;
    c1T[off] = acc;
}

// xT_all[t][k][b] = emb[ids[b][t]][k]   (t in [0,63))
__global__ __launch_bounds__(256) void gather_kernel(
    const int* __restrict__ ids, const float* __restrict__ emb,
    float* __restrict__ xT_all) {
    int idx = blockIdx.x * 256 + threadIdx.x;   // over TS*E*B
    int b = idx & (B - 1);
    int r = idx >> 6;
    int k = r & (E - 1);
    int t = r >> 9;                              // E = 512 = 2^9
    int row = ids[b * T + t];
    xT_all[idx] = emb[(size_t)row * E + k];
}

// One wave per output column j (lane = b). Computes 4 gate dots, updates c, h.
template<int KX>
__global__ __launch_bounds__(256) void lstm_cell_kernel(
    const float* __restrict__ xT, const float* __restrict__ hT_in,
    float* __restrict__ cT,
    const float* __restrict__ W_ih, const float* __restrict__ W_hh,
    const float* __restrict__ b_ih, const float* __restrict__ b_hh,
    float* __restrict__ hT_out) {
    const int lane = threadIdx.x & 63;
    int jw = blockIdx.x * 4 + (threadIdx.x >> 6);
    const int j = __builtin_amdgcn_readfirstlane(jw);

    float a0 = b_ih[j]         + b_hh[j];
    float a1 = b_ih[H + j]     + b_hh[H + j];
    float a2 = b_ih[2 * H + j] + b_hh[2 * H + j];
    float a3 = b_ih[3 * H + j] + b_hh[3 * H + j];

    const float* w0 = W_ih + (size_t)j * KX;
    const float* w1 = w0 + (size_t)H * KX;
    const float* w2 = w1 + (size_t)H * KX;
    const float* w3 = w2 + (size_t)H * KX;
    #pragma unroll 4
    for (int k = 0; k < KX; ++k) {
        float xv = xT[k * B + lane];
        a0 = fmaf(xv, w0[k], a0);
        a1 = fmaf(xv, w1[k], a1);
        a2 = fmaf(xv, w2[k], a2);
        a3 = fmaf(xv, w3[k], a3);
    }
    const float* u0 = W_hh + (size_t)j * H;
    const float* u1 = u0 + (size_t)H * H;
    const float* u2 = u1 + (size_t)H * H;
    const float* u3 = u2 + (size_t)H * H;
    #pragma unroll 4
    for (int k = 0; k < H; ++k) {
        float hv = hT_in[k * B + lane];
        a0 = fmaf(hv, u0[k], a0);
        a1 = fmaf(hv, u1[k], a1);
        a2 = fmaf(hv, u2[k], a2);
        a3 = fmaf(hv, u3[k], a3);
    }
    float ig = sigmoidf_(a0);
    float fg = sigmoidf_(a1);
    float gg = tanhf(a2);
    float og = sigmoidf_(a3);
    int off = j * B + lane;
    float cn = fg * cT[off] + ig * gg;
    cT[off] = cn;
    hT_out[off] = og * tanhf(cn);
}

// Batched logits GEMM: out[b][t][v] = sum_k h1_all[t][k][b] * proj_W[v][k] + proj_b[v]
// Block: fixed t, 128 v, all 64 b. 256 threads, micro-tile 8v x 4b.
#define VT 128
#define KC 32
__global__ __launch_bounds__(256) void logits_gemm_kernel(
    const float* __restrict__ h1_all, const float* __restrict__ proj_W,
    const float* __restrict__ proj_b, float* __restrict__ out) {
    __shared__ float As[KC][B];        // 8 KB
    __shared__ float Bs[VT][KC + 1];   // 16.5 KB, +1 pad
    const int t = blockIdx.y;
    const int v0 = blockIdx.x * VT;
    const int tid = threadIdx.x;
    const int tx = tid & 15;    // b group: b = tx*4 + ib
    const int ty = tid >> 4;    // v group: v = ty*8 + iv

    float acc[8][4];
    #pragma unroll
    for (int iv = 0; iv < 8; ++iv)
        #pragma unroll
        for (int ib = 0; ib < 4; ++ib) acc[iv][ib] = 0.0f;

    const float* hbase = h1_all + (size_t)t * H * B;
    for (int k0 = 0; k0 < H; k0 += KC) {
        #pragma unroll
        for (int i = 0; i < (KC * B) / 256; ++i) {
            int idx = tid + i * 256;
            As[idx >> 6][idx & 63] = hbase[k0 * B + idx];
        }
        #pragma unroll
        for (int i = 0; i < (VT * KC) / 256; ++i) {
            int idx = tid + i * 256;
            int vv = idx >> 5, kk = idx & 31;
            Bs[vv][kk] = proj_W[(size_t)(v0 + vv) * H + k0 + kk];
        }
        __syncthreads();
        #pragma unroll
        for (int kk = 0; kk < KC; ++kk) {
            float a[4], bb[8];
            #pragma unroll
            for (int ib = 0; ib < 4; ++ib) a[ib] = As[kk][tx * 4 + ib];
            #pragma unroll
            for (int iv = 0; iv < 8; ++iv) bb[iv] = Bs[ty * 8 + iv][kk];
            #pragma unroll
            for (int iv = 0; iv < 8; ++iv)
                #pragma unroll
                for (int ib = 0; ib < 4; ++ib)
                    acc[iv][ib] = fmaf(bb[iv], a[ib], acc[iv][ib]);
        }
        __syncthreads();
    }
    #pragma unroll
    for (int iv = 0; iv < 8; ++iv) {
        int v = v0 + ty * 8 + iv;
        float bias = proj_b[v];
        #pragma unroll
        for (int ib = 0; ib < 4; ++ib) {
            int b = tx * 4 + ib;
            out[((size_t)b * TS + t) * V + v] = acc[iv][ib] + bias;
        }
    }
}

// preds[b][t] = argmax_v logits[b][t][v]  (first index on ties)
__global__ __launch_bounds__(256) void argmax_kernel(
    const float* __restrict__ logits, float* __restrict__ preds) {
    int bt = blockIdx.x;
    const float* row = logits + (size_t)bt * V;
    float best = -1e30f;
    int bidx = 0;
    for (int v = threadIdx.x; v < V; v += 256) {
        float val = row[v];
        if (val > best) { best = val; bidx = v; }
    }
    __shared__ float sv[256];
    __shared__ int si[256];
    sv[threadIdx.x] = best;
    si[threadIdx.x] = bidx;
    __syncthreads();
    for (int s = 128; s > 0; s >>= 1) {
        if (threadIdx.x < s) {
            float o = sv[threadIdx.x + s];
            int oi = si[threadIdx.x + s];
            if (o > sv[threadIdx.x] ||
                (o == sv[threadIdx.x] && oi < si[threadIdx.x])) {
                sv[threadIdx.x] = o;
                si[threadIdx.x] = oi;
            }
        }
        __syncthreads();
    }
    if (threadIdx.x == 0) preds[bt] = (float)si[0];
}

extern "C" void kernel_launch(void* const* d_in, const int* in_sizes, int n_in,
                              void* d_out, int out_size, void* d_ws, size_t ws_size,
                              hipStream_t stream) {
    const int*   ids        = (const int*)d_in[0];
    const float* init_state = (const float*)d_in[1];
    const float* emb        = (const float*)d_in[2];
    const float* encW       = (const float*)d_in[3];
    const float* W_ih0      = (const float*)d_in[4];
    const float* W_hh0      = (const float*)d_in[5];
    const float* b_ih0      = (const float*)d_in[6];
    const float* b_hh0      = (const float*)d_in[7];
    const float* W_ih1      = (const float*)d_in[8];
    const float* W_hh1      = (const float*)d_in[9];
    const float* b_ih1      = (const float*)d_in[10];
    const float* b_hh1      = (const float*)d_in[11];
    const float* proj_W     = (const float*)d_in[12];
    const float* proj_b     = (const float*)d_in[13];

    float* out = (float*)d_out;
    float* preds = out;            // 64*63 floats
    float* logits = out + B * TS;  // 64*63*32000 floats

    float* ws = (float*)d_ws;
    float* sT      = ws;                        // EH*B
    float* h0_init = sT + EH * B;               // H*B
    float* h1_init = h0_init + H * B;           // H*B
    float* c0T     = h1_init + H * B;           // H*B
    float* c1T     = c0T + H * B;               // H*B
    float* xT_all  = c1T + H * B;               // TS*E*B
    float* h0_all  = xT_all + (size_t)TS * E * B;  // TS*H*B
    float* h1_all  = h0_all + (size_t)TS * H * B;  // TS*H*B

    transpose_init_kernel<<<(EH * B) / 256, 256, 0, stream>>>(init_state, sT);
    encoder_kernel<<<H / 4, 256, 0, stream>>>(sT, encW, h0_init, h1_init, c0T, c1T);
    gather_kernel<<<(TS * E * B) / 256, 256, 0, stream>>>(ids, emb, xT_all);

    for (int t = 0; t < TS; ++t) {
        const float* x0   = xT_all + (size_t)t * E * B;
        const float* h0in = t ? h0_all + (size_t)(t - 1) * H * B : h0_init;
        float* h0out      = h0_all + (size_t)t * H * B;
        lstm_cell_kernel<E><<<H / 4, 256, 0, stream>>>(
            x0, h0in, c0T, W_ih0, W_hh0, b_ih0, b_hh0, h0out);

        const float* h1in = t ? h1_all + (size_t)(t - 1) * H * B : h1_init;
        float* h1out      = h1_all + (size_t)t * H * B;
        lstm_cell_kernel<H><<<H / 4, 256, 0, stream>>>(
            h0out, h1in, c1T, W_ih1, W_hh1, b_ih1, b_hh1, h1out);
    }

    logits_gemm_kernel<<<dim3(V / VT, TS), 256, 0, stream>>>(
        h1_all, proj_W, proj_b, logits);
    argmax_kernel<<<B * TS, 256, 0, stream>>>(logits, preds);
}